// Round 5
// baseline (224.112 us; speedup 1.0000x reference)
//
#include <hip/hip_runtime.h>

// ---------------------------------------------------------------------------
// MultiHeadAttention: B=2, S=2048, E=1024, H=16, D=64
//   1. cast x -> bf16
//   2. transpose+cast w_in [K,N]->[N,K] bf16, w_out likewise
//   3. GEMM1: qkv[4096,3072] = x @ w_in + b_in (bf16; Q cols pre-scaled by
//      0.125*log2e so attention can use exp2 with no extra multiply)
//   4. transpose V part -> vt[b,h,d,s] bf16
//   5. flash attention (S^T form, no-max softmax, swizzled LDS, 64q/block,
//      lp accumulated via ones-MFMA)
//   6. GEMM2: out[4096,1024] = attn @ w_out + b_out (fp32 out)
// ---------------------------------------------------------------------------

typedef __bf16 bf16x8 __attribute__((ext_vector_type(8)));
typedef float  f32x4  __attribute__((ext_vector_type(4)));
typedef short  s16x4  __attribute__((ext_vector_type(4)));
typedef short  s16x8  __attribute__((ext_vector_type(8)));

__device__ __forceinline__ unsigned short f2b(float f) {
  unsigned u = __float_as_uint(f);
  unsigned r = u + 0x7fffu + ((u >> 16) & 1u);   // round-to-nearest-even
  return (unsigned short)(r >> 16);
}

// gfx950 HW packed fp32->bf16 convert (RNE): low16=cvt(a), high16=cvt(b).
__device__ __forceinline__ unsigned cvt_pk_bf16(float a, float b) {
#if defined(__HIP_DEVICE_COMPILE__)
  unsigned r;
  asm("v_cvt_pk_bf16_f32 %0, %1, %2" : "=v"(r) : "v"(a), "v"(b));
  return r;
#else
  return (unsigned)f2b(a) | ((unsigned)f2b(b) << 16);
#endif
}

// async global->LDS, 16 bytes per lane; HW writes lane i at lds + i*16.
__device__ __forceinline__ void gl_lds16(const void* g, void* l) {
  __builtin_amdgcn_global_load_lds(
      (__attribute__((address_space(1))) void*)g,
      (__attribute__((address_space(3))) void*)l, 16, 0, 0);
}

// 16x16x16 bf16 MFMA (K=16): B-operand layout B[n=lane&15][k=quad*4+j]
// matches the 16x16 C/D layout exactly -> softmax P feeds PV from registers.
__device__ __forceinline__ f32x4 mfma16x16x16(s16x4 a, s16x4 b, f32x4 c) {
#if defined(__HIP_DEVICE_COMPILE__)
#if __has_builtin(__builtin_amdgcn_mfma_f32_16x16x16bf16_1k)
  return __builtin_amdgcn_mfma_f32_16x16x16bf16_1k(a, b, c, 0, 0, 0);
#else
  // zero-padded K=32 fallback: k-slots j>=4 are 0 in both A and B -> exact.
  s16x8 a8 = {a[0], a[1], a[2], a[3], 0, 0, 0, 0};
  s16x8 b8 = {b[0], b[1], b[2], b[3], 0, 0, 0, 0};
  union U { s16x8 s; bf16x8 v; };
  U ua, ub; ua.s = a8; ub.s = b8;
  return __builtin_amdgcn_mfma_f32_16x16x32_bf16(ua.v, ub.v, c, 0, 0, 0);
#endif
#else
  (void)a; (void)b;
  return c;
#endif
}

// ---------------------------------------------------------------------------
__global__ __launch_bounds__(256) void cast_kernel(
    const float* __restrict__ in, unsigned short* __restrict__ out, int n4) {
  int i = blockIdx.x * 256 + threadIdx.x;
  if (i < n4) {
    float4 v = ((const float4*)in)[i];
    ushort4 o;
    o.x = f2b(v.x); o.y = f2b(v.y); o.z = f2b(v.z); o.w = f2b(v.w);
    ((ushort4*)out)[i] = o;
  }
}

// transpose + cast: in fp32 [R][C] -> out bf16 [C][R]. 64x64 tiles.
__global__ __launch_bounds__(256) void transpose_cast_kernel(
    const float* __restrict__ in, unsigned short* __restrict__ out, int R, int C) {
  __shared__ float tile[64][65];
  int r0 = blockIdx.y * 64, c0 = blockIdx.x * 64;
  int tid = threadIdx.x;
#pragma unroll
  for (int p = 0; p < 16; p++) {
    int i = tid + p * 256;
    int ri = i >> 6, ci = i & 63;
    tile[ri][ci] = in[(size_t)(r0 + ri) * C + c0 + ci];
  }
  __syncthreads();
#pragma unroll
  for (int p = 0; p < 16; p++) {
    int i = tid + p * 256;
    int ci = i >> 6, ri = i & 63;
    out[(size_t)(c0 + ci) * R + r0 + ri] = f2b(tile[ri][ci]);
  }
}

// V transpose: qkv[(b*2048+s)*3072 + 2048 + h*64 + d] -> vt[((b*16+h)*64+d)*2048 + s]
__global__ __launch_bounds__(256) void vt_transpose_kernel(
    const unsigned short* __restrict__ qkv, unsigned short* __restrict__ vt) {
  __shared__ unsigned short tile[64][65];
  int bid = blockIdx.x;
  int st = bid & 31, h = (bid >> 5) & 15, b = bid >> 9;
  int s0 = st * 64;
  int tid = threadIdx.x;
  const unsigned short* src = qkv + (size_t)(b * 2048 + s0) * 3072 + 2048 + h * 64;
#pragma unroll
  for (int p = 0; p < 16; p++) {
    int i = tid + p * 256;
    int sr = i >> 6, d = i & 63;
    tile[sr][d] = src[(size_t)sr * 3072 + d];
  }
  __syncthreads();
  unsigned short* dst = vt + (size_t)(b * 16 + h) * 64 * 2048 + s0;
#pragma unroll
  for (int p = 0; p < 16; p++) {
    int i = tid + p * 256;
    int dr = i >> 6, sc = i & 63;
    dst[(size_t)dr * 2048 + sc] = tile[sc][dr];
  }
}

// ---------------------------------------------------------------------------
// GEMM: C[M,N] = A[M,K] * Bt[N,K]^T + bias[N]. 128x128 tile, BK=32, m97 style.
// OUT_BF16: columns n < qcols additionally scaled by qscale (Q pre-scaling).
// ---------------------------------------------------------------------------
template <int OUT_BF16>
__global__ __launch_bounds__(256) void gemm_bt(
    const unsigned short* __restrict__ A, const unsigned short* __restrict__ Bt,
    const float* __restrict__ bias, void* __restrict__ Cp, int M, int N, int K,
    int qcols, float qscale) {
  __shared__ __align__(16) unsigned short As[128 * 32];
  __shared__ __align__(16) unsigned short Bs[128 * 32];
  int tid = threadIdx.x;
  int wave = tid >> 6, lane = tid & 63;
  int m_l = lane & 15, quad = lane >> 4;
  int wm = (wave >> 1) * 64, wn = (wave & 1) * 64;
  int row = tid >> 2, kp = (tid & 3) << 3;
  const unsigned short* ag = A + (size_t)(blockIdx.y * 128 + row) * K + kp;
  const unsigned short* bg = Bt + (size_t)(blockIdx.x * 128 + row) * K + kp;
  unsigned short* asw = As + wave * 512;
  unsigned short* bsw = Bs + wave * 512;
  f32x4 acc[4][4] = {};
  for (int k0 = 0; k0 < K; k0 += 32) {
    __syncthreads();
    gl_lds16(ag + k0, asw);
    gl_lds16(ag + (size_t)64 * K + k0, asw + 2048);
    gl_lds16(bg + k0, bsw);
    gl_lds16(bg + (size_t)64 * K + k0, bsw + 2048);
    __syncthreads();
    bf16x8 af[4], bf[4];
#pragma unroll
    for (int i = 0; i < 4; i++)
      af[i] = *(const bf16x8*)&As[(wm + i * 16 + m_l) * 32 + quad * 8];
#pragma unroll
    for (int j = 0; j < 4; j++)
      bf[j] = *(const bf16x8*)&Bs[(wn + j * 16 + m_l) * 32 + quad * 8];
#pragma unroll
    for (int i = 0; i < 4; i++)
#pragma unroll
      for (int j = 0; j < 4; j++)
        acc[i][j] = __builtin_amdgcn_mfma_f32_16x16x32_bf16(af[i], bf[j], acc[i][j], 0, 0, 0);
  }
  float bv[4];
#pragma unroll
  for (int j = 0; j < 4; j++) bv[j] = bias[blockIdx.x * 128 + wn + j * 16 + m_l];
#pragma unroll
  for (int i = 0; i < 4; i++) {
    int m = blockIdx.y * 128 + wm + i * 16 + quad * 4;
#pragma unroll
    for (int j = 0; j < 4; j++) {
      int n = blockIdx.x * 128 + wn + j * 16 + m_l;
      float sc = (OUT_BF16 && n < qcols) ? qscale : 1.0f;
#pragma unroll
      for (int r = 0; r < 4; r++) {
        float v = (acc[i][j][r] + bv[j]) * sc;
        if (OUT_BF16)
          ((unsigned short*)Cp)[(size_t)(m + r) * N + n] = f2b(v);
        else
          ((float*)Cp)[(size_t)(m + r) * N + n] = v;
      }
    }
  }
}

// ---------------------------------------------------------------------------
// Flash attention, S^T formulation, 256 threads (4 waves x 16 queries = 64 q).
// Grid 1024 -> 4 blocks/CU (16 waves/CU) for barrier-stall coverage.
// Per 64-key tile:
//   S^T = K Q^T via 16x16x32 (C: col=q, row=key);
//   no-max softmax p=exp2(s) (Q pre-scaled by 0.125*log2e in GEMM1);
//   P packed with v_cvt_pk_bf16_f32;
//   PV as O^T = V^T P^T via 16x16x16 (P frag == softmax C frag);
//   lp accumulated by a 5th MFMA with all-ones A (kills VALU adds+shuffles).
// K/V/Q staged via global_load_lds, XOR-swizzled chunks (conflict-free).
// ---------------------------------------------------------------------------
__global__ __launch_bounds__(256) void attn_kernel(
    const unsigned short* __restrict__ qkv, const unsigned short* __restrict__ vt,
    unsigned short* __restrict__ aout) {
  __shared__ __align__(16) unsigned short Qs[64 * 64];   // [q][d] swizzled
  __shared__ __align__(16) unsigned short Ks[64 * 64];   // [key][d] swizzled
  __shared__ __align__(16) unsigned short Vts[64 * 64];  // [d][key] swizzled
  int bid = blockIdx.x;
  int qt = bid & 31, h = (bid >> 5) & 15, b = bid >> 9;
  int tid = threadIdx.x, wave = tid >> 6;
  int lane = tid & 63;
  int m_l = lane & 15, quad = lane >> 4;
  int q0 = qt * 64;
  const unsigned short* qb = qkv + (size_t)b * 2048 * 3072 + h * 64;
  const unsigned short* kb = qb + 1024;
  const unsigned short* vtb = vt + (size_t)(b * 16 + h) * 64 * 2048;

  // staging: 256 threads cover 32 rows x 8 chunks per round (2 rounds/tile);
  // fetch global chunk (tid&7)^(srow&7) so LDS[row][c] = global chunk c^(row&7).
  int srow = tid >> 3;                      // 0..31
  int sd0 = ((tid & 7) ^ (srow & 7)) * 8;

  // stage Q[64][64]: rounds r=0,1 cover rows r*32+srow
  gl_lds16(qb + (size_t)(q0 + srow) * 3072 + sd0, Qs + wave * 512);
  gl_lds16(qb + (size_t)(q0 + 32 + srow) * 3072 + sd0, Qs + 2048 + wave * 512);
  __syncthreads();

  // swizzled read offsets for d-chunks quad and quad+4 (row&7 == m_l&7)
  int ml7 = m_l & 7;
  int sw0 = ((quad ^ ml7) * 8);
  int sw1 = (((quad + 4) ^ ml7) * 8);

  int qrow = (wave * 16 + m_l) * 64;
  bf16x8 qf0 = *(const bf16x8*)&Qs[qrow + sw0];
  bf16x8 qf1 = *(const bf16x8*)&Qs[qrow + sw1];

  // hoisted bases
  int kbase = m_l * 64;                   // + sw0/sw1 + t*1024 (imm)
  int vbase = m_l * 64 + (quad & 1) * 4;  // + kchunk(t)*8 + dt*1024 (imm)
  int qh = quad >> 1;

  const s16x4 ones = {0x3F80, 0x3F80, 0x3F80, 0x3F80};  // bf16 1.0 x4

  f32x4 o[4] = {};   // O^T accumulators per d-tile
  f32x4 lacc = {};   // lp accumulator (all rows identical)

  for (int kt = 0; kt < 2048; kt += 64) {
    __syncthreads();
    gl_lds16(kb + (size_t)(kt + srow) * 3072 + sd0, Ks + wave * 512);
    gl_lds16(kb + (size_t)(kt + 32 + srow) * 3072 + sd0, Ks + 2048 + wave * 512);
    gl_lds16(vtb + (size_t)srow * 2048 + kt + sd0, Vts + wave * 512);
    gl_lds16(vtb + (size_t)(32 + srow) * 2048 + kt + sd0, Vts + 2048 + wave * 512);
    __syncthreads();

#pragma unroll
    for (int t = 0; t < 4; t++) {
      bf16x8 kf0 = *(const bf16x8*)&Ks[kbase + t * 1024 + sw0];
      bf16x8 kf1 = *(const bf16x8*)&Ks[kbase + t * 1024 + sw1];
      f32x4 z = {};
      f32x4 s = __builtin_amdgcn_mfma_f32_16x16x32_bf16(kf0, qf0, z, 0, 0, 0);
      s = __builtin_amdgcn_mfma_f32_16x16x32_bf16(kf1, qf1, s, 0, 0, 0);
      union { uint2 u; s16x4 s4; } pk;
      pk.u.x = cvt_pk_bf16(__builtin_exp2f(s[0]), __builtin_exp2f(s[1]));
      pk.u.y = cvt_pk_bf16(__builtin_exp2f(s[2]), __builtin_exp2f(s[3]));
      lacc = mfma16x16x16(ones, pk.s4, lacc);
      int voff = vbase + (((t * 2 + qh) ^ ml7) * 8);
      // PV: A = V^T[d][key] (4 contiguous keys per lane), B = pfrag
#pragma unroll
      for (int dt = 0; dt < 4; dt++) {
        s16x4 vf = *(const s16x4*)&Vts[voff + dt * 1024];
        o[dt] = mfma16x16x16(vf, pk.s4, o[dt]);
      }
    }
  }

  // lp: MFMA summed over all 16 keys per call across quads -> complete in reg 0
  float rl = 1.0f / lacc[0];

  // epilogue: O^T frag (col=q=lane&15, row=d=quad*4+r) -> aout[q][h*64+d]
  unsigned short* ob = aout + (size_t)(b * 2048 + q0 + wave * 16 + m_l) * 1024 +
                       h * 64 + quad * 4;
#pragma unroll
  for (int dt = 0; dt < 4; dt++) {
    union { uint2 u; ushort4 w; } pk;
    pk.u.x = cvt_pk_bf16(o[dt][0] * rl, o[dt][1] * rl);
    pk.u.y = cvt_pk_bf16(o[dt][2] * rl, o[dt][3] * rl);
    *(ushort4*)&ob[dt * 16] = pk.w;
  }
}

// ---------------------------------------------------------------------------
extern "C" void kernel_launch(void* const* d_in, const int* in_sizes, int n_in,
                              void* d_out, int out_size, void* d_ws, size_t ws_size,
                              hipStream_t stream) {
  (void)in_sizes; (void)n_in; (void)out_size; (void)ws_size;
  const float* x     = (const float*)d_in[0];
  const float* w_in  = (const float*)d_in[1];
  const float* b_in  = (const float*)d_in[2];
  const float* w_out = (const float*)d_in[3];
  const float* b_out = (const float*)d_in[4];
  char* ws = (char*)d_ws;
  unsigned short* xb    = (unsigned short*)(ws + 0);          //  8 MB
  unsigned short* wint  = (unsigned short*)(ws + 8388608);    //  6 MB
  unsigned short* woutt = (unsigned short*)(ws + 14680064);   //  2 MB
  unsigned short* qkv   = (unsigned short*)(ws + 16777216);   // 24 MB
  unsigned short* vt    = (unsigned short*)(ws + 41943040);   //  8 MB
  unsigned short* attn  = (unsigned short*)(ws + 50331648);   //  8 MB
  float* out = (float*)d_out;

  const float QSCALE = 0.125f * 1.44269504088896f;  // fold 1/sqrt(64) * log2(e)

  cast_kernel<<<4096, 256, 0, stream>>>(x, xb, 1048576);
  transpose_cast_kernel<<<dim3(48, 16), 256, 0, stream>>>(w_in, wint, 1024, 3072);
  transpose_cast_kernel<<<dim3(16, 16), 256, 0, stream>>>(w_out, woutt, 1024, 1024);
  gemm_bt<1><<<dim3(24, 32), 256, 0, stream>>>(xb, wint, b_in, qkv, 4096, 3072, 1024,
                                               1024, QSCALE);
  vt_transpose_kernel<<<1024, 256, 0, stream>>>(qkv, vt);
  attn_kernel<<<1024, 256, 0, stream>>>(qkv, vt, attn);
  gemm_bt<0><<<dim3(8, 32), 256, 0, stream>>>(attn, woutt, b_out, out, 4096, 1024, 1024,
                                              0, 1.0f);
}

// Round 8
// 210.949 us; speedup vs baseline: 1.0624x; 1.0624x over previous
//
#include <hip/hip_runtime.h>

// ---------------------------------------------------------------------------
// MultiHeadAttention: B=2, S=2048, E=1024, H=16, D=64
//   1. prep_kernel (fused): cast x->bf16; transpose+cast w_in, w_out
//   2. GEMM1: qkv[4096,3072] = x @ w_in + b_in (bf16; Q cols pre-scaled by
//      0.125*log2e so attention can use exp2 with no extra multiply)
//   3. transpose V part -> vt[b,h,d,s] bf16
//   4. flash attention (R4-verified: S^T form, no-max softmax, swizzled LDS,
//      512 thr, 8 waves x 16 q, grid 512)
//   5. GEMM2: out[4096,1024] = attn @ w_out + b_out (fp32 out; 128x64 tiles,
//      512 blocks = 2/CU vs 1/CU at 128x128)
// ---------------------------------------------------------------------------

typedef __bf16 bf16x8 __attribute__((ext_vector_type(8)));
typedef float  f32x4  __attribute__((ext_vector_type(4)));
typedef short  s16x4  __attribute__((ext_vector_type(4)));
typedef short  s16x8  __attribute__((ext_vector_type(8)));

__device__ __forceinline__ unsigned short f2b(float f) {
  unsigned u = __float_as_uint(f);
  unsigned r = u + 0x7fffu + ((u >> 16) & 1u);   // round-to-nearest-even
  return (unsigned short)(r >> 16);
}

// gfx950 HW packed fp32->bf16 convert (RNE): low16=cvt(a), high16=cvt(b).
__device__ __forceinline__ unsigned cvt_pk_bf16(float a, float b) {
#if defined(__HIP_DEVICE_COMPILE__)
  unsigned r;
  asm("v_cvt_pk_bf16_f32 %0, %1, %2" : "=v"(r) : "v"(a), "v"(b));
  return r;
#else
  return (unsigned)f2b(a) | ((unsigned)f2b(b) << 16);
#endif
}

// async global->LDS, 16 bytes per lane; HW writes lane i at lds + i*16.
__device__ __forceinline__ void gl_lds16(const void* g, void* l) {
  __builtin_amdgcn_global_load_lds(
      (__attribute__((address_space(1))) void*)g,
      (__attribute__((address_space(3))) void*)l, 16, 0, 0);
}

// 16x16x16 bf16 MFMA (K=16): B-operand layout B[n=lane&15][k=quad*4+j]
// matches the 16x16 C/D layout exactly -> softmax P feeds PV from registers.
__device__ __forceinline__ f32x4 mfma16x16x16(s16x4 a, s16x4 b, f32x4 c) {
#if defined(__HIP_DEVICE_COMPILE__)
#if __has_builtin(__builtin_amdgcn_mfma_f32_16x16x16bf16_1k)
  return __builtin_amdgcn_mfma_f32_16x16x16bf16_1k(a, b, c, 0, 0, 0);
#else
  // zero-padded K=32 fallback: k-slots j>=4 are 0 in both A and B -> exact.
  s16x8 a8 = {a[0], a[1], a[2], a[3], 0, 0, 0, 0};
  s16x8 b8 = {b[0], b[1], b[2], b[3], 0, 0, 0, 0};
  union U { s16x8 s; bf16x8 v; };
  U ua, ub; ua.s = a8; ub.s = b8;
  return __builtin_amdgcn_mfma_f32_16x16x32_bf16(ua.v, ub.v, c, 0, 0, 0);
#endif
#else
  (void)a; (void)b;
  return c;
#endif
}

// ---------------------------------------------------------------------------
// prep_kernel: fused elementwise cast (x->xb) + two transpose_cast jobs.
// grid 5120 x 256: [0,4096) cast; [4096,4864) w_in T; [4864,5120) w_out T.
// ---------------------------------------------------------------------------
__device__ __forceinline__ void transpose_cast_body(
    const float* __restrict__ in, unsigned short* __restrict__ out,
    int R, int C, int bx, int by, int tid, float tile[64][65]) {
  int r0 = by * 64, c0 = bx * 64;
#pragma unroll
  for (int p = 0; p < 16; p++) {
    int i = tid + p * 256;
    int ri = i >> 6, ci = i & 63;
    tile[ri][ci] = in[(size_t)(r0 + ri) * C + c0 + ci];
  }
  __syncthreads();
#pragma unroll
  for (int p = 0; p < 16; p++) {
    int i = tid + p * 256;
    int ci = i >> 6, ri = i & 63;
    out[(size_t)(c0 + ci) * R + r0 + ri] = f2b(tile[ri][ci]);
  }
}

__global__ __launch_bounds__(256) void prep_kernel(
    const float* __restrict__ x, unsigned short* __restrict__ xb,
    const float* __restrict__ w_in, unsigned short* __restrict__ wint,
    const float* __restrict__ w_out, unsigned short* __restrict__ woutt) {
  __shared__ float tile[64][65];
  int bid = blockIdx.x, tid = threadIdx.x;
  if (bid < 4096) {
    int i = bid * 256 + tid;   // n4 = 1048576 exactly = 4096*256
    float4 v = ((const float4*)x)[i];
    ushort4 o;
    o.x = f2b(v.x); o.y = f2b(v.y); o.z = f2b(v.z); o.w = f2b(v.w);
    ((ushort4*)xb)[i] = o;
  } else if (bid < 4864) {
    int l = bid - 4096;        // 768 blocks: (48 x, 16 y)
    transpose_cast_body(w_in, wint, 1024, 3072, l % 48, l / 48, tid, tile);
  } else {
    int l = bid - 4864;        // 256 blocks: (16 x, 16 y)
    transpose_cast_body(w_out, woutt, 1024, 1024, l % 16, l / 16, tid, tile);
  }
}

// V transpose: qkv[(b*2048+s)*3072 + 2048 + h*64 + d] -> vt[((b*16+h)*64+d)*2048 + s]
__global__ __launch_bounds__(256) void vt_transpose_kernel(
    const unsigned short* __restrict__ qkv, unsigned short* __restrict__ vt) {
  __shared__ unsigned short tile[64][65];
  int bid = blockIdx.x;
  int st = bid & 31, h = (bid >> 5) & 15, b = bid >> 9;
  int s0 = st * 64;
  int tid = threadIdx.x;
  const unsigned short* src = qkv + (size_t)(b * 2048 + s0) * 3072 + 2048 + h * 64;
#pragma unroll
  for (int p = 0; p < 16; p++) {
    int i = tid + p * 256;
    int sr = i >> 6, d = i & 63;
    tile[sr][d] = src[(size_t)sr * 3072 + d];
  }
  __syncthreads();
  unsigned short* dst = vt + (size_t)(b * 16 + h) * 64 * 2048 + s0;
#pragma unroll
  for (int p = 0; p < 16; p++) {
    int i = tid + p * 256;
    int dr = i >> 6, sc = i & 63;
    dst[(size_t)dr * 2048 + sc] = tile[sc][dr];
  }
}

// ---------------------------------------------------------------------------
// GEMM1: C[M,N] = A[M,K]*Bt[N,K]^T + bias[N], bf16 out. 128x128 tile, BK=32.
// Columns n < qcols scaled by qscale (Q pre-scaling for exp2 softmax).
// ---------------------------------------------------------------------------
__global__ __launch_bounds__(256) void gemm_bt1(
    const unsigned short* __restrict__ A, const unsigned short* __restrict__ Bt,
    const float* __restrict__ bias, unsigned short* __restrict__ Cp,
    int M, int N, int K, int qcols, float qscale) {
  __shared__ __align__(16) unsigned short As[128 * 32];
  __shared__ __align__(16) unsigned short Bs[128 * 32];
  int tid = threadIdx.x;
  int wave = tid >> 6, lane = tid & 63;
  int m_l = lane & 15, quad = lane >> 4;
  int wm = (wave >> 1) * 64, wn = (wave & 1) * 64;
  int row = tid >> 2, kp = (tid & 3) << 3;
  const unsigned short* ag = A + (size_t)(blockIdx.y * 128 + row) * K + kp;
  const unsigned short* bg = Bt + (size_t)(blockIdx.x * 128 + row) * K + kp;
  unsigned short* asw = As + wave * 512;
  unsigned short* bsw = Bs + wave * 512;
  f32x4 acc[4][4] = {};
  for (int k0 = 0; k0 < K; k0 += 32) {
    __syncthreads();
    gl_lds16(ag + k0, asw);
    gl_lds16(ag + (size_t)64 * K + k0, asw + 2048);
    gl_lds16(bg + k0, bsw);
    gl_lds16(bg + (size_t)64 * K + k0, bsw + 2048);
    __syncthreads();
    bf16x8 af[4], bf[4];
#pragma unroll
    for (int i = 0; i < 4; i++)
      af[i] = *(const bf16x8*)&As[(wm + i * 16 + m_l) * 32 + quad * 8];
#pragma unroll
    for (int j = 0; j < 4; j++)
      bf[j] = *(const bf16x8*)&Bs[(wn + j * 16 + m_l) * 32 + quad * 8];
#pragma unroll
    for (int i = 0; i < 4; i++)
#pragma unroll
      for (int j = 0; j < 4; j++)
        acc[i][j] = __builtin_amdgcn_mfma_f32_16x16x32_bf16(af[i], bf[j], acc[i][j], 0, 0, 0);
  }
  float bv[4];
#pragma unroll
  for (int j = 0; j < 4; j++) bv[j] = bias[blockIdx.x * 128 + wn + j * 16 + m_l];
#pragma unroll
  for (int i = 0; i < 4; i++) {
    int m = blockIdx.y * 128 + wm + i * 16 + quad * 4;
#pragma unroll
    for (int j = 0; j < 4; j++) {
      int n = blockIdx.x * 128 + wn + j * 16 + m_l;
      float sc = (n < qcols) ? qscale : 1.0f;
#pragma unroll
      for (int r = 0; r < 4; r++) {
        float v = (acc[i][j][r] + bv[j]) * sc;
        Cp[(size_t)(m + r) * N + n] = f2b(v);
      }
    }
  }
}

// ---------------------------------------------------------------------------
// GEMM2: C[M,N] = A[M,K]*Bt[N,K]^T + bias[N], fp32 out. 128x64 tile, BK=32.
// Grid (N/64, M/128) = (16,32) = 512 blocks -> 2 blocks/CU (vs 1 at 128x128).
// Wave layout: 2x2 of (64m x 32n); 8 MFMA + 6 ds_read_b128 per wave-K-step.
// ---------------------------------------------------------------------------
__global__ __launch_bounds__(256) void gemm_bt2(
    const unsigned short* __restrict__ A, const unsigned short* __restrict__ Bt,
    const float* __restrict__ bias, float* __restrict__ Cp, int M, int N, int K) {
  __shared__ __align__(16) unsigned short As[128 * 32];
  __shared__ __align__(16) unsigned short Bs[64 * 32];
  int tid = threadIdx.x;
  int wave = tid >> 6, lane = tid & 63;
  int m_l = lane & 15, quad = lane >> 4;
  int wm = (wave >> 1) * 64, wn = (wave & 1) * 32;
  int row = tid >> 2, kp = (tid & 3) << 3;
  const unsigned short* ag = A + (size_t)(blockIdx.y * 128 + row) * K + kp;
  const unsigned short* bg = Bt + (size_t)(blockIdx.x * 64 + row) * K + kp;
  unsigned short* asw = As + wave * 512;
  unsigned short* bsw = Bs + wave * 512;
  f32x4 acc[4][2] = {};
  for (int k0 = 0; k0 < K; k0 += 32) {
    __syncthreads();
    gl_lds16(ag + k0, asw);
    gl_lds16(ag + (size_t)64 * K + k0, asw + 2048);
    gl_lds16(bg + k0, bsw);
    __syncthreads();
    bf16x8 af[4], bf[2];
#pragma unroll
    for (int i = 0; i < 4; i++)
      af[i] = *(const bf16x8*)&As[(wm + i * 16 + m_l) * 32 + quad * 8];
#pragma unroll
    for (int j = 0; j < 2; j++)
      bf[j] = *(const bf16x8*)&Bs[(wn + j * 16 + m_l) * 32 + quad * 8];
#pragma unroll
    for (int i = 0; i < 4; i++)
#pragma unroll
      for (int j = 0; j < 2; j++)
        acc[i][j] = __builtin_amdgcn_mfma_f32_16x16x32_bf16(af[i], bf[j], acc[i][j], 0, 0, 0);
  }
  float bv[2];
#pragma unroll
  for (int j = 0; j < 2; j++) bv[j] = bias[blockIdx.x * 64 + wn + j * 16 + m_l];
#pragma unroll
  for (int i = 0; i < 4; i++) {
    int m = blockIdx.y * 128 + wm + i * 16 + quad * 4;
#pragma unroll
    for (int j = 0; j < 2; j++) {
      int n = blockIdx.x * 64 + wn + j * 16 + m_l;
#pragma unroll
      for (int r = 0; r < 4; r++)
        Cp[(size_t)(m + r) * N + n] = acc[i][j][r] + bv[j];
    }
  }
}

// ---------------------------------------------------------------------------
// Flash attention (R4-verified). 512 threads = 8 waves x 16 queries = 128 q.
// Grid 512. Per 64-key tile:
//   S^T = K Q^T via 16x16x32 (C: col=q, row=key);
//   no-max softmax p=exp2(s) (Q pre-scaled by 0.125*log2e in GEMM1);
//   P packed with v_cvt_pk_bf16_f32;
//   PV as O^T = V^T P^T via 16x16x16 (P frag == softmax C frag, no movement).
// K/V/Q staged via global_load_lds, XOR-swizzled chunks (conflict-free).
// ---------------------------------------------------------------------------
__global__ __launch_bounds__(512) void attn_kernel(
    const unsigned short* __restrict__ qkv, const unsigned short* __restrict__ vt,
    unsigned short* __restrict__ aout) {
  __shared__ __align__(16) unsigned short Qs[128 * 64];  // [q][d] swizzled
  __shared__ __align__(16) unsigned short Ks[64 * 64];   // [key][d] swizzled
  __shared__ __align__(16) unsigned short Vts[64 * 64];  // [d][key] swizzled
  int bid = blockIdx.x;
  int qt = bid & 15, h = (bid >> 4) & 15, b = bid >> 8;
  int tid = threadIdx.x, wave = tid >> 6;
  int lane = tid & 63;
  int m_l = lane & 15, quad = lane >> 4;
  int q0 = qt * 128;
  const unsigned short* qb = qkv + (size_t)b * 2048 * 3072 + h * 64;
  const unsigned short* kb = qb + 1024;
  const unsigned short* vtb = vt + (size_t)(b * 16 + h) * 64 * 2048;

  // staging: 512 threads cover 64 rows x 8 chunks; fetch global chunk
  // (tid&7)^(row&7) so LDS[row][c] holds global chunk c^(row&7).
  int srow = tid >> 3;                      // 0..63
  int sd0 = ((tid & 7) ^ (srow & 7)) * 8;

  // stage Q[128][64]: 2 rounds of 64 rows
  gl_lds16(qb + (size_t)(q0 + srow) * 3072 + sd0, Qs + wave * 512);
  gl_lds16(qb + (size_t)(q0 + 64 + srow) * 3072 + sd0, Qs + 4096 + wave * 512);
  __syncthreads();

  // swizzled read offsets for d-chunks quad and quad+4 (row&7 == m_l&7)
  int sw0 = ((quad ^ (m_l & 7)) * 8);
  int sw1 = (((quad + 4) ^ (m_l & 7)) * 8);

  int qrow = (wave * 16 + m_l) * 64;
  bf16x8 qf0 = *(const bf16x8*)&Qs[qrow + sw0];
  bf16x8 qf1 = *(const bf16x8*)&Qs[qrow + sw1];

  f32x4 o[4] = {};   // O^T accumulators per d-tile
  float lp = 0.f;    // softmax denominator (per q = lane&15)

  for (int kt = 0; kt < 2048; kt += 64) {
    __syncthreads();
    gl_lds16(kb + (size_t)(kt + srow) * 3072 + sd0, Ks + wave * 512);
    gl_lds16(vtb + (size_t)srow * 2048 + kt + sd0, Vts + wave * 512);
    __syncthreads();

#pragma unroll
    for (int t = 0; t < 4; t++) {
      int kr = (t * 16 + m_l) * 64;
      bf16x8 kf0 = *(const bf16x8*)&Ks[kr + sw0];
      bf16x8 kf1 = *(const bf16x8*)&Ks[kr + sw1];
      f32x4 z = {};
      f32x4 s = __builtin_amdgcn_mfma_f32_16x16x32_bf16(kf0, qf0, z, 0, 0, 0);
      s = __builtin_amdgcn_mfma_f32_16x16x32_bf16(kf1, qf1, s, 0, 0, 0);
      float p0 = __builtin_exp2f(s[0]);
      float p1 = __builtin_exp2f(s[1]);
      float p2 = __builtin_exp2f(s[2]);
      float p3 = __builtin_exp2f(s[3]);
      lp += (p0 + p1) + (p2 + p3);
      union { uint2 u; s16x4 s4; } pk;
      pk.u.x = cvt_pk_bf16(p0, p1);
      pk.u.y = cvt_pk_bf16(p2, p3);
      // PV: A = V^T[d][key] (4 contiguous keys per lane), B = pfrag
#pragma unroll
      for (int dt = 0; dt < 4; dt++) {
        int drow = dt * 16 + m_l;
        int kchunk = (t * 2 + (quad >> 1)) ^ (m_l & 7);
        s16x4 vf = *(const s16x4*)&Vts[drow * 64 + kchunk * 8 + (quad & 1) * 4];
        o[dt] = mfma16x16x16(vf, pk.s4, o[dt]);
      }
    }
  }

  // reduce denominator across quads (q lives at lane&15 in all quads)
  lp += __shfl_xor(lp, 16, 64);
  lp += __shfl_xor(lp, 32, 64);
  float rl = 1.0f / lp;

  // epilogue: O^T frag (col=q=lane&15, row=d=quad*4+r) -> aout[q][h*64+d]
  unsigned short* ob = aout + (size_t)(b * 2048 + q0 + wave * 16 + m_l) * 1024 +
                       h * 64 + quad * 4;
#pragma unroll
  for (int dt = 0; dt < 4; dt++) {
    union { uint2 u; ushort4 w; } pk;
    pk.u.x = cvt_pk_bf16(o[dt][0] * rl, o[dt][1] * rl);
    pk.u.y = cvt_pk_bf16(o[dt][2] * rl, o[dt][3] * rl);
    *(ushort4*)&ob[dt * 16] = pk.w;
  }
}

// ---------------------------------------------------------------------------
extern "C" void kernel_launch(void* const* d_in, const int* in_sizes, int n_in,
                              void* d_out, int out_size, void* d_ws, size_t ws_size,
                              hipStream_t stream) {
  (void)in_sizes; (void)n_in; (void)out_size; (void)ws_size;
  const float* x     = (const float*)d_in[0];
  const float* w_in  = (const float*)d_in[1];
  const float* b_in  = (const float*)d_in[2];
  const float* w_out = (const float*)d_in[3];
  const float* b_out = (const float*)d_in[4];
  char* ws = (char*)d_ws;
  unsigned short* xb    = (unsigned short*)(ws + 0);          //  8 MB
  unsigned short* wint  = (unsigned short*)(ws + 8388608);    //  6 MB
  unsigned short* woutt = (unsigned short*)(ws + 14680064);   //  2 MB
  unsigned short* qkv   = (unsigned short*)(ws + 16777216);   // 24 MB
  unsigned short* vt    = (unsigned short*)(ws + 41943040);   //  8 MB
  unsigned short* attn  = (unsigned short*)(ws + 50331648);   //  8 MB
  float* out = (float*)d_out;

  const float QSCALE = 0.125f * 1.44269504088896f;  // fold 1/sqrt(64) * log2(e)

  prep_kernel<<<5120, 256, 0, stream>>>(x, xb, w_in, wint, w_out, woutt);
  gemm_bt1<<<dim3(24, 32), 256, 0, stream>>>(xb, wint, b_in, qkv, 4096, 3072, 1024,
                                             1024, QSCALE);
  vt_transpose_kernel<<<1024, 256, 0, stream>>>(qkv, vt);
  attn_kernel<<<512, 512, 0, stream>>>(qkv, vt, attn);
  gemm_bt2<<<dim3(16, 32), 256, 0, stream>>>(attn, woutt, b_out, out, 4096, 1024, 1024);
}

// Round 10
// 209.757 us; speedup vs baseline: 1.0684x; 1.0057x over previous
//
#include <hip/hip_runtime.h>

// ---------------------------------------------------------------------------
// MultiHeadAttention: B=2, S=2048, E=1024, H=16, D=64
//   1. prep_kernel (fused): cast x->bf16; transpose+cast w_in, w_out
//   2. GEMM1: qkv[4096,3072] = x @ w_in + b_in (bf16; Q cols pre-scaled by
//      0.125*log2e so attention can use exp2 with no extra multiply)
//   3. transpose V part -> vt[b,h,d,s] bf16
//   4. flash attention (R8 skeleton + R5-verified ones-MFMA lp + hoisted
//      LDS addressing; __builtin_exp2f — raw v_exp_f32 builtin FAILED R9)
//   5. GEMM2: out[4096,1024] = attn @ w_out + b_out (fp32 out; 128x64 tiles)
// ---------------------------------------------------------------------------

typedef __bf16 bf16x8 __attribute__((ext_vector_type(8)));
typedef float  f32x4  __attribute__((ext_vector_type(4)));
typedef short  s16x4  __attribute__((ext_vector_type(4)));
typedef short  s16x8  __attribute__((ext_vector_type(8)));

__device__ __forceinline__ unsigned short f2b(float f) {
  unsigned u = __float_as_uint(f);
  unsigned r = u + 0x7fffu + ((u >> 16) & 1u);   // round-to-nearest-even
  return (unsigned short)(r >> 16);
}

// gfx950 HW packed fp32->bf16 convert (RNE): low16=cvt(a), high16=cvt(b).
__device__ __forceinline__ unsigned cvt_pk_bf16(float a, float b) {
#if defined(__HIP_DEVICE_COMPILE__)
  unsigned r;
  asm("v_cvt_pk_bf16_f32 %0, %1, %2" : "=v"(r) : "v"(a), "v"(b));
  return r;
#else
  return (unsigned)f2b(a) | ((unsigned)f2b(b) << 16);
#endif
}

// async global->LDS, 16 bytes per lane; HW writes lane i at lds + i*16.
__device__ __forceinline__ void gl_lds16(const void* g, void* l) {
  __builtin_amdgcn_global_load_lds(
      (__attribute__((address_space(1))) void*)g,
      (__attribute__((address_space(3))) void*)l, 16, 0, 0);
}

// 16x16x16 bf16 MFMA (K=16): B-operand layout B[n=lane&15][k=quad*4+j]
// matches the 16x16 C/D layout exactly -> softmax P feeds PV from registers.
__device__ __forceinline__ f32x4 mfma16x16x16(s16x4 a, s16x4 b, f32x4 c) {
#if defined(__HIP_DEVICE_COMPILE__)
#if __has_builtin(__builtin_amdgcn_mfma_f32_16x16x16bf16_1k)
  return __builtin_amdgcn_mfma_f32_16x16x16bf16_1k(a, b, c, 0, 0, 0);
#else
  // zero-padded K=32 fallback: k-slots j>=4 are 0 in both A and B -> exact.
  s16x8 a8 = {a[0], a[1], a[2], a[3], 0, 0, 0, 0};
  s16x8 b8 = {b[0], b[1], b[2], b[3], 0, 0, 0, 0};
  union U { s16x8 s; bf16x8 v; };
  U ua, ub; ua.s = a8; ub.s = b8;
  return __builtin_amdgcn_mfma_f32_16x16x32_bf16(ua.v, ub.v, c, 0, 0, 0);
#endif
#else
  (void)a; (void)b;
  return c;
#endif
}

// ---------------------------------------------------------------------------
// prep_kernel: fused elementwise cast (x->xb) + two transpose_cast jobs.
// grid 5120 x 256: [0,4096) cast; [4096,4864) w_in T; [4864,5120) w_out T.
// ---------------------------------------------------------------------------
__device__ __forceinline__ void transpose_cast_body(
    const float* __restrict__ in, unsigned short* __restrict__ out,
    int R, int C, int bx, int by, int tid, float tile[64][65]) {
  int r0 = by * 64, c0 = bx * 64;
#pragma unroll
  for (int p = 0; p < 16; p++) {
    int i = tid + p * 256;
    int ri = i >> 6, ci = i & 63;
    tile[ri][ci] = in[(size_t)(r0 + ri) * C + c0 + ci];
  }
  __syncthreads();
#pragma unroll
  for (int p = 0; p < 16; p++) {
    int i = tid + p * 256;
    int ci = i >> 6, ri = i & 63;
    out[(size_t)(c0 + ci) * R + r0 + ri] = f2b(tile[ri][ci]);
  }
}

__global__ __launch_bounds__(256) void prep_kernel(
    const float* __restrict__ x, unsigned short* __restrict__ xb,
    const float* __restrict__ w_in, unsigned short* __restrict__ wint,
    const float* __restrict__ w_out, unsigned short* __restrict__ woutt) {
  __shared__ float tile[64][65];
  int bid = blockIdx.x, tid = threadIdx.x;
  if (bid < 4096) {
    int i = bid * 256 + tid;   // n4 = 1048576 exactly = 4096*256
    float4 v = ((const float4*)x)[i];
    ushort4 o;
    o.x = f2b(v.x); o.y = f2b(v.y); o.z = f2b(v.z); o.w = f2b(v.w);
    ((ushort4*)xb)[i] = o;
  } else if (bid < 4864) {
    int l = bid - 4096;        // 768 blocks: (48 x, 16 y)
    transpose_cast_body(w_in, wint, 1024, 3072, l % 48, l / 48, tid, tile);
  } else {
    int l = bid - 4864;        // 256 blocks: (16 x, 16 y)
    transpose_cast_body(w_out, woutt, 1024, 1024, l % 16, l / 16, tid, tile);
  }
}

// V transpose: qkv[(b*2048+s)*3072 + 2048 + h*64 + d] -> vt[((b*16+h)*64+d)*2048 + s]
__global__ __launch_bounds__(256) void vt_transpose_kernel(
    const unsigned short* __restrict__ qkv, unsigned short* __restrict__ vt) {
  __shared__ unsigned short tile[64][65];
  int bid = blockIdx.x;
  int st = bid & 31, h = (bid >> 5) & 15, b = bid >> 9;
  int s0 = st * 64;
  int tid = threadIdx.x;
  const unsigned short* src = qkv + (size_t)(b * 2048 + s0) * 3072 + 2048 + h * 64;
#pragma unroll
  for (int p = 0; p < 16; p++) {
    int i = tid + p * 256;
    int sr = i >> 6, d = i & 63;
    tile[sr][d] = src[(size_t)sr * 3072 + d];
  }
  __syncthreads();
  unsigned short* dst = vt + (size_t)(b * 16 + h) * 64 * 2048 + s0;
#pragma unroll
  for (int p = 0; p < 16; p++) {
    int i = tid + p * 256;
    int dr = i >> 6, sc = i & 63;
    dst[(size_t)dr * 2048 + sc] = tile[sc][dr];
  }
}

// ---------------------------------------------------------------------------
// GEMM1: C[M,N] = A[M,K]*Bt[N,K]^T + bias[N], bf16 out. 128x128 tile, BK=32.
// Columns n < qcols scaled by qscale (Q pre-scaling for exp2 softmax).
// ---------------------------------------------------------------------------
__global__ __launch_bounds__(256) void gemm_bt1(
    const unsigned short* __restrict__ A, const unsigned short* __restrict__ Bt,
    const float* __restrict__ bias, unsigned short* __restrict__ Cp,
    int M, int N, int K, int qcols, float qscale) {
  __shared__ __align__(16) unsigned short As[128 * 32];
  __shared__ __align__(16) unsigned short Bs[128 * 32];
  int tid = threadIdx.x;
  int wave = tid >> 6, lane = tid & 63;
  int m_l = lane & 15, quad = lane >> 4;
  int wm = (wave >> 1) * 64, wn = (wave & 1) * 64;
  int row = tid >> 2, kp = (tid & 3) << 3;
  const unsigned short* ag = A + (size_t)(blockIdx.y * 128 + row) * K + kp;
  const unsigned short* bg = Bt + (size_t)(blockIdx.x * 128 + row) * K + kp;
  unsigned short* asw = As + wave * 512;
  unsigned short* bsw = Bs + wave * 512;
  f32x4 acc[4][4] = {};
  for (int k0 = 0; k0 < K; k0 += 32) {
    __syncthreads();
    gl_lds16(ag + k0, asw);
    gl_lds16(ag + (size_t)64 * K + k0, asw + 2048);
    gl_lds16(bg + k0, bsw);
    gl_lds16(bg + (size_t)64 * K + k0, bsw + 2048);
    __syncthreads();
    bf16x8 af[4], bf[4];
#pragma unroll
    for (int i = 0; i < 4; i++)
      af[i] = *(const bf16x8*)&As[(wm + i * 16 + m_l) * 32 + quad * 8];
#pragma unroll
    for (int j = 0; j < 4; j++)
      bf[j] = *(const bf16x8*)&Bs[(wn + j * 16 + m_l) * 32 + quad * 8];
#pragma unroll
    for (int i = 0; i < 4; i++)
#pragma unroll
      for (int j = 0; j < 4; j++)
        acc[i][j] = __builtin_amdgcn_mfma_f32_16x16x32_bf16(af[i], bf[j], acc[i][j], 0, 0, 0);
  }
  float bv[4];
#pragma unroll
  for (int j = 0; j < 4; j++) bv[j] = bias[blockIdx.x * 128 + wn + j * 16 + m_l];
#pragma unroll
  for (int i = 0; i < 4; i++) {
    int m = blockIdx.y * 128 + wm + i * 16 + quad * 4;
#pragma unroll
    for (int j = 0; j < 4; j++) {
      int n = blockIdx.x * 128 + wn + j * 16 + m_l;
      float sc = (n < qcols) ? qscale : 1.0f;
#pragma unroll
      for (int r = 0; r < 4; r++) {
        float v = (acc[i][j][r] + bv[j]) * sc;
        Cp[(size_t)(m + r) * N + n] = f2b(v);
      }
    }
  }
}

// ---------------------------------------------------------------------------
// GEMM2: C[M,N] = A[M,K]*Bt[N,K]^T + bias[N], fp32 out. 128x64 tile, BK=32.
// Grid (N/64, M/128) = (16,32) = 512 blocks -> 2 blocks/CU.
// ---------------------------------------------------------------------------
__global__ __launch_bounds__(256) void gemm_bt2(
    const unsigned short* __restrict__ A, const unsigned short* __restrict__ Bt,
    const float* __restrict__ bias, float* __restrict__ Cp, int M, int N, int K) {
  __shared__ __align__(16) unsigned short As[128 * 32];
  __shared__ __align__(16) unsigned short Bs[64 * 32];
  int tid = threadIdx.x;
  int wave = tid >> 6, lane = tid & 63;
  int m_l = lane & 15, quad = lane >> 4;
  int wm = (wave >> 1) * 64, wn = (wave & 1) * 32;
  int row = tid >> 2, kp = (tid & 3) << 3;
  const unsigned short* ag = A + (size_t)(blockIdx.y * 128 + row) * K + kp;
  const unsigned short* bg = Bt + (size_t)(blockIdx.x * 64 + row) * K + kp;
  unsigned short* asw = As + wave * 512;
  unsigned short* bsw = Bs + wave * 512;
  f32x4 acc[4][2] = {};
  for (int k0 = 0; k0 < K; k0 += 32) {
    __syncthreads();
    gl_lds16(ag + k0, asw);
    gl_lds16(ag + (size_t)64 * K + k0, asw + 2048);
    gl_lds16(bg + k0, bsw);
    __syncthreads();
    bf16x8 af[4], bf[2];
#pragma unroll
    for (int i = 0; i < 4; i++)
      af[i] = *(const bf16x8*)&As[(wm + i * 16 + m_l) * 32 + quad * 8];
#pragma unroll
    for (int j = 0; j < 2; j++)
      bf[j] = *(const bf16x8*)&Bs[(wn + j * 16 + m_l) * 32 + quad * 8];
#pragma unroll
    for (int i = 0; i < 4; i++)
#pragma unroll
      for (int j = 0; j < 2; j++)
        acc[i][j] = __builtin_amdgcn_mfma_f32_16x16x32_bf16(af[i], bf[j], acc[i][j], 0, 0, 0);
  }
  float bv[2];
#pragma unroll
  for (int j = 0; j < 2; j++) bv[j] = bias[blockIdx.x * 64 + wn + j * 16 + m_l];
#pragma unroll
  for (int i = 0; i < 4; i++) {
    int m = blockIdx.y * 128 + wm + i * 16 + quad * 4;
#pragma unroll
    for (int j = 0; j < 2; j++) {
      int n = blockIdx.x * 64 + wn + j * 16 + m_l;
#pragma unroll
      for (int r = 0; r < 4; r++)
        Cp[(size_t)(m + r) * N + n] = acc[i][j][r] + bv[j];
    }
  }
}

// ---------------------------------------------------------------------------
// Flash attention. 512 threads = 8 waves x 16 queries = 128 q. Grid 512.
// R8-verified skeleton + R5-verified ones-MFMA lp + hoisted addressing.
// __builtin_exp2f (raw __builtin_amdgcn_exp2f produced 2.2e-2 absmax in R9 —
// do NOT use it).
// Per 64-key tile:
//   S^T = K Q^T via 16x16x32 (C: col=q, row=key);
//   no-max softmax p=exp2(s) (Q pre-scaled by 0.125*log2e in GEMM1);
//   P packed with v_cvt_pk_bf16_f32;
//   PV as O^T = V^T P^T via 16x16x16 (P frag == softmax C frag, no movement);
//   lp accumulated by ones-MFMA (complete per-q sum in every acc element).
// K/V/Q staged via global_load_lds, XOR-swizzled chunks (conflict-free).
// ---------------------------------------------------------------------------
__global__ __launch_bounds__(512) void attn_kernel(
    const unsigned short* __restrict__ qkv, const unsigned short* __restrict__ vt,
    unsigned short* __restrict__ aout) {
  __shared__ __align__(16) unsigned short Qs[128 * 64];  // [q][d] swizzled
  __shared__ __align__(16) unsigned short Ks[64 * 64];   // [key][d] swizzled
  __shared__ __align__(16) unsigned short Vts[64 * 64];  // [d][key] swizzled
  int bid = blockIdx.x;
  int qt = bid & 15, h = (bid >> 4) & 15, b = bid >> 8;
  int tid = threadIdx.x, wave = tid >> 6;
  int lane = tid & 63;
  int m_l = lane & 15, quad = lane >> 4;
  int q0 = qt * 128;
  const unsigned short* qb = qkv + (size_t)b * 2048 * 3072 + h * 64;
  const unsigned short* kb = qb + 1024;
  const unsigned short* vtb = vt + (size_t)(b * 16 + h) * 64 * 2048;

  // staging: 512 threads cover 64 rows x 8 chunks; fetch global chunk
  // (tid&7)^(row&7) so LDS[row][c] holds global chunk c^(row&7).
  int srow = tid >> 3;                      // 0..63
  int sd0 = ((tid & 7) ^ (srow & 7)) * 8;

  // stage Q[128][64]: 2 rounds of 64 rows
  gl_lds16(qb + (size_t)(q0 + srow) * 3072 + sd0, Qs + wave * 512);
  gl_lds16(qb + (size_t)(q0 + 64 + srow) * 3072 + sd0, Qs + 4096 + wave * 512);
  __syncthreads();

  // swizzled read offsets for d-chunks quad and quad+4 (row&7 == m_l&7)
  int ml7 = m_l & 7;
  int sw0 = ((quad ^ ml7) * 8);
  int sw1 = (((quad + 4) ^ ml7) * 8);

  int qrow = (wave * 16 + m_l) * 64;
  bf16x8 qf0 = *(const bf16x8*)&Qs[qrow + sw0];
  bf16x8 qf1 = *(const bf16x8*)&Qs[qrow + sw1];

  // hoisted read bases (verified R5): kf at kbase + t*1024 + sw{0,1};
  // vf at vbase + swz(t)*8 + dt*1024.
  int kbase = m_l * 64;
  int vbase = m_l * 64 + (quad & 1) * 4;
  int qh = quad >> 1;

  const s16x4 ones = {0x3F80, 0x3F80, 0x3F80, 0x3F80};  // bf16 1.0 x4

  f32x4 o[4] = {};   // O^T accumulators per d-tile
  f32x4 lacc = {};   // lp accumulator (every element = full per-q sum)

  for (int kt = 0; kt < 2048; kt += 64) {
    __syncthreads();
    gl_lds16(kb + (size_t)(kt + srow) * 3072 + sd0, Ks + wave * 512);
    gl_lds16(vtb + (size_t)srow * 2048 + kt + sd0, Vts + wave * 512);
    __syncthreads();

#pragma unroll
    for (int t = 0; t < 4; t++) {
      bf16x8 kf0 = *(const bf16x8*)&Ks[kbase + t * 1024 + sw0];
      bf16x8 kf1 = *(const bf16x8*)&Ks[kbase + t * 1024 + sw1];
      f32x4 z = {};
      f32x4 s = __builtin_amdgcn_mfma_f32_16x16x32_bf16(kf0, qf0, z, 0, 0, 0);
      s = __builtin_amdgcn_mfma_f32_16x16x32_bf16(kf1, qf1, s, 0, 0, 0);
      union { uint2 u; s16x4 s4; } pk;
      pk.u.x = cvt_pk_bf16(__builtin_exp2f(s[0]), __builtin_exp2f(s[1]));
      pk.u.y = cvt_pk_bf16(__builtin_exp2f(s[2]), __builtin_exp2f(s[3]));
      lacc = mfma16x16x16(ones, pk.s4, lacc);
      int voff = vbase + (((t * 2 + qh) ^ ml7) * 8);
      // PV: A = V^T[d][key] (4 contiguous keys per lane), B = pfrag
#pragma unroll
      for (int dt = 0; dt < 4; dt++) {
        s16x4 vf = *(const s16x4*)&Vts[voff + dt * 1024];
        o[dt] = mfma16x16x16(vf, pk.s4, o[dt]);
      }
    }
  }

  // lp: ones-MFMA summed over all keys and quads -> complete in element 0
  float rl = 1.0f / lacc[0];

  // epilogue: O^T frag (col=q=lane&15, row=d=quad*4+r) -> aout[q][h*64+d]
  unsigned short* ob = aout + (size_t)(b * 2048 + q0 + wave * 16 + m_l) * 1024 +
                       h * 64 + quad * 4;
#pragma unroll
  for (int dt = 0; dt < 4; dt++) {
    union { uint2 u; ushort4 w; } pk;
    pk.u.x = cvt_pk_bf16(o[dt][0] * rl, o[dt][1] * rl);
    pk.u.y = cvt_pk_bf16(o[dt][2] * rl, o[dt][3] * rl);
    *(ushort4*)&ob[dt * 16] = pk.w;
  }
}

// ---------------------------------------------------------------------------
extern "C" void kernel_launch(void* const* d_in, const int* in_sizes, int n_in,
                              void* d_out, int out_size, void* d_ws, size_t ws_size,
                              hipStream_t stream) {
  (void)in_sizes; (void)n_in; (void)out_size; (void)ws_size;
  const float* x     = (const float*)d_in[0];
  const float* w_in  = (const float*)d_in[1];
  const float* b_in  = (const float*)d_in[2];
  const float* w_out = (const float*)d_in[3];
  const float* b_out = (const float*)d_in[4];
  char* ws = (char*)d_ws;
  unsigned short* xb    = (unsigned short*)(ws + 0);          //  8 MB
  unsigned short* wint  = (unsigned short*)(ws + 8388608);    //  6 MB
  unsigned short* woutt = (unsigned short*)(ws + 14680064);   //  2 MB
  unsigned short* qkv   = (unsigned short*)(ws + 16777216);   // 24 MB
  unsigned short* vt    = (unsigned short*)(ws + 41943040);   //  8 MB
  unsigned short* attn  = (unsigned short*)(ws + 50331648);   //  8 MB
  float* out = (float*)d_out;

  const float QSCALE = 0.125f * 1.44269504088896f;  // fold 1/sqrt(64) * log2(e)

  prep_kernel<<<5120, 256, 0, stream>>>(x, xb, w_in, wint, w_out, woutt);
  gemm_bt1<<<dim3(24, 32), 256, 0, stream>>>(xb, wint, b_in, qkv, 4096, 3072, 1024,
                                             1024, QSCALE);
  vt_transpose_kernel<<<1024, 256, 0, stream>>>(qkv, vt);
  attn_kernel<<<512, 512, 0, stream>>>(qkv, vt, attn);
  gemm_bt2<<<dim3(16, 32), 256, 0, stream>>>(attn, woutt, b_out, out, 4096, 1024, 1024);
}